// Round 1
// baseline (1930.007 us; speedup 1.0000x reference)
//
#include <hip/hip_runtime.h>

#define H 256

// ---------- kernel A: zero counters ----------
__global__ void k_zero(int* cnt, int n) {
  int i = blockIdx.x * blockDim.x + threadIdx.x;
  if (i < n) cnt[i] = 0;
}

// ---------- kernel B: histogram of edge destinations ----------
__global__ void k_hist(const int* __restrict__ dst, int* __restrict__ cnt, int ne) {
  int e = blockIdx.x * blockDim.x + threadIdx.x;
  if (e < ne) atomicAdd(&cnt[dst[e]], 1);
}

// ---------- kernel C: single-block exclusive scan (n <= ~1M fine) ----------
__global__ __launch_bounds__(1024) void k_scan(const int* __restrict__ cnt,
                                               int* __restrict__ offs,
                                               int* __restrict__ cursor, int n) {
  __shared__ int lsum[1024];
  int t = threadIdx.x;
  int ch = (n + 1023) >> 10;
  int beg = t * ch;
  int end = min(beg + ch, n);
  int s = 0;
  for (int i = beg; i < end; ++i) s += cnt[i];
  lsum[t] = s;
  __syncthreads();
  for (int off = 1; off < 1024; off <<= 1) {
    int v = (t >= off) ? lsum[t - off] : 0;
    __syncthreads();
    lsum[t] += v;
    __syncthreads();
  }
  int base = (t > 0) ? lsum[t - 1] : 0;
  for (int i = beg; i < end; ++i) {
    offs[i] = base;
    cursor[i] = base;
    base += cnt[i];
  }
  if (t == 1023) offs[n] = lsum[1023];
}

// ---------- kernel D: fill CSR buckets (pack src|rel<<16; src<65536 here) ----
__global__ void k_fill(const int* __restrict__ src, const int* __restrict__ dst,
                       const int* __restrict__ rel, int* __restrict__ cursor,
                       int* __restrict__ bucket, int ne) {
  int e = blockIdx.x * blockDim.x + threadIdx.x;
  if (e < ne) {
    int p = atomicAdd(&cursor[dst[e]], 1);
    bucket[p] = src[e] | (rel[e] << 16);
  }
}

// ---------- kernel E: per-node gather-reduce (one wave per node) ----------
__global__ __launch_bounds__(256) void k_gather(const float* __restrict__ h,
                                                const float* __restrict__ relv,
                                                const int* __restrict__ offs,
                                                const int* __restrict__ bucket,
                                                float* __restrict__ red, int nn) {
  int wave = threadIdx.x >> 6;
  int lane = threadIdx.x & 63;
  int node = blockIdx.x * 4 + wave;
  if (node >= nn) return;
  int beg = offs[node], end = offs[node + 1];
  float4 acc = make_float4(0.f, 0.f, 0.f, 0.f);
  for (int i = beg; i < end; ++i) {
    int p = bucket[i];
    int s = p & 0xFFFF;
    int r = p >> 16;
    float4 hv = *(const float4*)&h[s * H + lane * 4];
    float4 rv = *(const float4*)&relv[r * H + lane * 4];
    acc.x += hv.x + rv.x;
    acc.y += hv.y + rv.y;
    acc.z += hv.z + rv.z;
    acc.w += hv.w + rv.w;
  }
  *(float4*)&red[node * H + lane * 4] = acc;
}

// ---------- kernel F: fused dual-GEMM + GRU pointwise ----------
// block 256 threads (16x16). BM=64 rows. 8 col-chunks of 32 h-cols.
// 6 accumulation tiles: {r,z,n} x {ih(red), hh(h)}. K=256 in 8 steps of 32.
__global__ __launch_bounds__(256) void k_gru(const float* __restrict__ red,
                                             const float* __restrict__ hmat,
                                             const float* __restrict__ w_ih,
                                             const float* __restrict__ w_hh,
                                             const float* __restrict__ b_ih,
                                             const float* __restrict__ b_hh,
                                             float* __restrict__ out, int nn) {
  __shared__ float a_s[2][64][34];   // [red/h][row][k] pad 34 (even: float2-aligned)
  __shared__ float w_s[6][32][34];   // [gate-tile][col][k]
  int tid = threadIdx.x;
  int ty = tid >> 4, tx = tid & 15;
  int row0 = blockIdx.x * 64;

  for (int cc = 0; cc < 8; ++cc) {
    float acc[6][4][2];
#pragma unroll
    for (int g = 0; g < 6; ++g)
#pragma unroll
      for (int i = 0; i < 4; ++i)
#pragma unroll
        for (int j = 0; j < 2; ++j) acc[g][i][j] = 0.f;

    for (int kb = 0; kb < 8; ++kb) {
      // A tiles: red/h [64][32]
#pragma unroll
      for (int it = 0; it < 2; ++it) {
        int v = tid + it * 256;
        int r = v >> 3, c4 = (v & 7) * 4;
        int row = row0 + r;
        float4 fr = make_float4(0.f, 0.f, 0.f, 0.f);
        float4 fh = make_float4(0.f, 0.f, 0.f, 0.f);
        if (row < nn) {
          fr = *(const float4*)&red[row * H + kb * 32 + c4];
          fh = *(const float4*)&hmat[row * H + kb * 32 + c4];
        }
        *(float2*)&a_s[0][r][c4]     = make_float2(fr.x, fr.y);
        *(float2*)&a_s[0][r][c4 + 2] = make_float2(fr.z, fr.w);
        *(float2*)&a_s[1][r][c4]     = make_float2(fh.x, fh.y);
        *(float2*)&a_s[1][r][c4 + 2] = make_float2(fh.z, fh.w);
      }
      // W tiles: 6 x [32 cols][32 k]
      {
        int col = tid >> 3, c4 = (tid & 7) * 4;
#pragma unroll
        for (int g = 0; g < 6; ++g) {
          const float* w = (g < 3) ? w_ih : w_hh;
          int gg = (g < 3) ? g : g - 3;
          float4 f = *(const float4*)&w[(gg * 256 + cc * 32 + col) * H + kb * 32 + c4];
          *(float2*)&w_s[g][col][c4]     = make_float2(f.x, f.y);
          *(float2*)&w_s[g][col][c4 + 2] = make_float2(f.z, f.w);
        }
      }
      __syncthreads();
#pragma unroll
      for (int k = 0; k < 32; k += 2) {
        float2 ar[4], ah[4], wv[6][2];
#pragma unroll
        for (int i = 0; i < 4; ++i) {
          ar[i] = *(const float2*)&a_s[0][ty * 4 + i][k];
          ah[i] = *(const float2*)&a_s[1][ty * 4 + i][k];
        }
#pragma unroll
        for (int g = 0; g < 6; ++g)
#pragma unroll
          for (int j = 0; j < 2; ++j) wv[g][j] = *(const float2*)&w_s[g][tx * 2 + j][k];
#pragma unroll
        for (int i = 0; i < 4; ++i)
#pragma unroll
          for (int j = 0; j < 2; ++j) {
#pragma unroll
            for (int g = 0; g < 3; ++g) {
              acc[g][i][j] += ar[i].x * wv[g][j].x;
              acc[g][i][j] += ar[i].y * wv[g][j].y;
            }
#pragma unroll
            for (int g = 3; g < 6; ++g) {
              acc[g][i][j] += ah[i].x * wv[g][j].x;
              acc[g][i][j] += ah[i].y * wv[g][j].y;
            }
          }
      }
      __syncthreads();
    }
    // fused GRU epilogue for this col-chunk
#pragma unroll
    for (int i = 0; i < 4; ++i) {
      int row = row0 + ty * 4 + i;
      if (row >= nn) continue;
#pragma unroll
      for (int j = 0; j < 2; ++j) {
        int col = cc * 32 + tx * 2 + j;
        float gir = acc[0][i][j] + b_ih[col];
        float giz = acc[1][i][j] + b_ih[256 + col];
        float gin = acc[2][i][j] + b_ih[512 + col];
        float ghr = acc[3][i][j] + b_hh[col];
        float ghz = acc[4][i][j] + b_hh[256 + col];
        float ghn = acc[5][i][j] + b_hh[512 + col];
        float rr = 1.f / (1.f + __expf(-(gir + ghr)));
        float zz = 1.f / (1.f + __expf(-(giz + ghz)));
        float n_ = tanhf(gin + rr * ghn);
        float hv = hmat[row * H + col];
        out[row * H + col] = (1.f - zz) * n_ + zz * hv;
      }
    }
  }
}

extern "C" void kernel_launch(void* const* d_in, const int* in_sizes, int n_in,
                              void* d_out, int out_size, void* d_ws, size_t ws_size,
                              hipStream_t stream) {
  const float* h    = (const float*)d_in[0];
  const float* relv = (const float*)d_in[1];
  const float* w_ih = (const float*)d_in[2];
  const float* w_hh = (const float*)d_in[3];
  const float* b_ih = (const float*)d_in[4];
  const float* b_hh = (const float*)d_in[5];
  const int* esrc   = (const int*)d_in[6];
  const int* edst   = (const int*)d_in[7];
  const int* erel   = (const int*)d_in[8];
  float* out = (float*)d_out;
  int nn = in_sizes[0] / H;   // 50000
  int ne = in_sizes[6];       // 800000

  // workspace layout
  float* red  = (float*)d_ws;                       // nn*H floats
  int* cnt    = (int*)(red + (size_t)nn * H);       // nn
  int* offs   = cnt + nn;                           // nn+1
  int* cursor = offs + nn + 1;                      // nn
  int* bucket = cursor + nn;                        // ne

  k_zero<<<(nn + 255) / 256, 256, 0, stream>>>(cnt, nn);
  k_hist<<<(ne + 255) / 256, 256, 0, stream>>>(edst, cnt, ne);
  k_scan<<<1, 1024, 0, stream>>>(cnt, offs, cursor, nn);
  k_fill<<<(ne + 255) / 256, 256, 0, stream>>>(esrc, edst, erel, cursor, bucket, ne);
  k_gather<<<(nn + 3) / 4, 256, 0, stream>>>(h, relv, offs, bucket, red, nn);
  k_gru<<<(nn + 63) / 64, 256, 0, stream>>>(red, h, w_ih, w_hh, b_ih, b_hh, out, nn);
}

// Round 2
// 706.108 us; speedup vs baseline: 2.7333x; 2.7333x over previous
//
#include <hip/hip_runtime.h>
#include <hip/hip_bf16.h>

#define H 256
#define BM 64
#define NW 6
#define TPB 384

typedef __attribute__((ext_vector_type(8))) short short8;
typedef __attribute__((ext_vector_type(4))) float f32x4;

__device__ __forceinline__ ushort f2bf(float f) {
  unsigned u = __float_as_uint(f);
  unsigned r = (u + 0x7fffu + ((u >> 16) & 1u)) >> 16;
  return (ushort)r;
}
__device__ __forceinline__ float bf2f(ushort s) {
  return __uint_as_float(((unsigned)s) << 16);
}

__device__ __forceinline__ void gld_lds16(const void* g, void* lds) {
  __builtin_amdgcn_global_load_lds(
      (const __attribute__((address_space(1))) unsigned int*)g,
      (__attribute__((address_space(3))) unsigned int*)lds, 16, 0, 0);
}

// ---------- f32 -> bf16 convert ----------
__global__ void k_cvt(const float* __restrict__ src, ushort* __restrict__ dst, int n4) {
  int i = blockIdx.x * blockDim.x + threadIdx.x;
  if (i < n4) {
    float4 f = *(const float4*)&src[(size_t)i * 4];
    ushort4 o;
    o.x = f2bf(f.x); o.y = f2bf(f.y); o.z = f2bf(f.z); o.w = f2bf(f.w);
    *(ushort4*)&dst[(size_t)i * 4] = o;
  }
}

// ---------- CSR build ----------
__global__ void k_zero(int* cnt, int n) {
  int i = blockIdx.x * blockDim.x + threadIdx.x;
  if (i < n) cnt[i] = 0;
}

__global__ void k_hist(const int* __restrict__ dst, int* __restrict__ cnt, int ne) {
  int e = blockIdx.x * blockDim.x + threadIdx.x;
  if (e < ne) atomicAdd(&cnt[dst[e]], 1);
}

__global__ __launch_bounds__(1024) void k_scan(const int* __restrict__ cnt,
                                               int* __restrict__ offs,
                                               int* __restrict__ cursor, int n) {
  __shared__ int lsum[1024];
  int t = threadIdx.x;
  int ch = (n + 1023) >> 10;
  int beg = t * ch;
  int end = min(beg + ch, n);
  int s = 0;
  for (int i = beg; i < end; ++i) s += cnt[i];
  lsum[t] = s;
  __syncthreads();
  for (int off = 1; off < 1024; off <<= 1) {
    int v = (t >= off) ? lsum[t - off] : 0;
    __syncthreads();
    lsum[t] += v;
    __syncthreads();
  }
  int base = (t > 0) ? lsum[t - 1] : 0;
  for (int i = beg; i < end; ++i) {
    offs[i] = base;
    cursor[i] = base;
    base += cnt[i];
  }
  if (t == 1023) offs[n] = lsum[1023];
}

__global__ void k_fill(const int* __restrict__ src, const int* __restrict__ dst,
                       const int* __restrict__ rel, int* __restrict__ cursor,
                       int* __restrict__ bucket, int ne) {
  int e = blockIdx.x * blockDim.x + threadIdx.x;
  if (e < ne) {
    int p = atomicAdd(&cursor[dst[e]], 1);
    bucket[p] = src[e] | (rel[e] << 16);
  }
}

// ---------- gather-reduce (bf16 h in, bf16 red out, f32 accum) ----------
__global__ __launch_bounds__(256) void k_gather(const ushort* __restrict__ h16,
                                                const float* __restrict__ relv,
                                                const int* __restrict__ offs,
                                                const int* __restrict__ bucket,
                                                ushort* __restrict__ red16, int nn) {
  int wave = threadIdx.x >> 6;
  int lane = threadIdx.x & 63;
  int node = blockIdx.x * 4 + wave;
  if (node >= nn) return;
  int beg = offs[node], end = offs[node + 1];
  float ax = 0.f, ay = 0.f, az = 0.f, aw = 0.f;
  for (int i = beg; i < end; ++i) {
    int p = bucket[i];
    int s = p & 0xFFFF;
    int r = p >> 16;
    ushort4 hv = *(const ushort4*)&h16[(size_t)s * H + lane * 4];
    float4 rv = *(const float4*)&relv[(size_t)r * H + lane * 4];
    ax += bf2f(hv.x) + rv.x;
    ay += bf2f(hv.y) + rv.y;
    az += bf2f(hv.z) + rv.z;
    aw += bf2f(hv.w) + rv.w;
  }
  ushort4 o;
  o.x = f2bf(ax); o.y = f2bf(ay); o.z = f2bf(az); o.w = f2bf(aw);
  *(ushort4*)&red16[(size_t)node * H + lane * 4] = o;
}

// ---------- fused dual-GEMM (bf16 MFMA) + GRU epilogue ----------
// LDS map (bytes):
//   A_red [64 rows][8 slots*16B] swizzled      @ 0      (8 KB)
//   A_h   same                                 @ 8192   (8 KB)
//   W     [192 cols][8 slots*16B] swizzled     @ 16384  (24 KB)
//   stash ushort [64][192]                     @ 40960  (24 KB)   => 64 KB total
#define A_RED_OFF 0
#define A_H_OFF   8192
#define W_OFF     16384
#define STASH_OFF 40960
#define STASH_LD  192

__global__ __launch_bounds__(TPB, 3) void k_gru_mfma(
    const ushort* __restrict__ red16, const ushort* __restrict__ h16,
    const float* __restrict__ hmat,
    const ushort* __restrict__ wih16, const ushort* __restrict__ whh16,
    const float* __restrict__ b_ih, const float* __restrict__ b_hh,
    float* __restrict__ out, int nn) {
  __shared__ unsigned char smem[65536];
  const int tid = threadIdx.x;
  const int wid = tid >> 6;
  const int lane = tid & 63;
  const int ln15 = lane & 15;
  const int l4 = lane >> 4;
  const int sx = ln15 & 7;       // swizzle xor (row&7 == ln15&7 since tiles are 16-row aligned)
  const int row0 = blockIdx.x * BM;
  const int s_sub = lane >> 3;   // staging: row-within-8-group
  const int s_slot = lane & 7;   // staging: 16B slot

  ushort* stash = (ushort*)&smem[STASH_OFF];

  for (int cc = 0; cc < 8; ++cc) {
    f32x4 acc[4][2] = {};

    for (int kb = 0; kb < 4; ++kb) {
      // ---- stage A (16 x 1KB) + W (24 x 1KB) via global_load_lds ----
      for (int i = wid; i < 40; i += NW) {
        if (i < 16) {
          const int mat = i >> 3;
          const int r8 = i & 7;
          const int trow = r8 * 8 + s_sub;
          int grow = row0 + trow;
          if (grow >= nn) grow = nn - 1;
          const ushort* base = mat ? h16 : red16;
          const ushort* src = base + (size_t)grow * H + kb * 64 + ((s_slot ^ (trow & 7)) * 8);
          gld_lds16(src, &smem[(mat ? A_H_OFF : A_RED_OFF) + r8 * 1024]);
        } else {
          const int wq = i - 16;            // 0..23
          const int c = wq * 8 + s_sub;     // 0..191 (strip-local gate col)
          const int g = c >> 5;             // strip 0..5
          const int cis = c & 31;
          const int wrow = (g >= 3 ? g - 3 : g) * 256 + cc * 32 + cis;
          const ushort* wm = (g >= 3) ? whh16 : wih16;
          const ushort* src = wm + (size_t)wrow * H + kb * 64 + ((s_slot ^ (c & 7)) * 8);
          gld_lds16(src, &smem[W_OFF + wq * 1024]);
        }
      }
      __syncthreads();
      // ---- compute: wave `wid` = gate strip wid; 4 row-tiles x 2 col-tiles ----
      const int abase = (wid < 3) ? A_RED_OFF : A_H_OFF;
#pragma unroll
      for (int t = 0; t < 2; ++t) {
        const int slot = ((t * 4 + l4) ^ sx) * 16;
        short8 a[4], b[2];
#pragma unroll
        for (int rt = 0; rt < 4; ++rt)
          a[rt] = *(const short8*)&smem[abase + (rt * 16 + ln15) * 128 + slot];
#pragma unroll
        for (int ct = 0; ct < 2; ++ct)
          b[ct] = *(const short8*)&smem[W_OFF + (wid * 32 + ct * 16 + ln15) * 128 + slot];
#pragma unroll
        for (int rt = 0; rt < 4; ++rt)
#pragma unroll
          for (int ct = 0; ct < 2; ++ct)
            acc[rt][ct] = __builtin_amdgcn_mfma_f32_16x16x32_bf16(a[rt], b[ct], acc[rt][ct], 0, 0, 0);
      }
      __syncthreads();
    }

    // ---- stash gates as bf16: C frag row=(l>>4)*4+r, col=l&15 ----
#pragma unroll
    for (int rt = 0; rt < 4; ++rt)
#pragma unroll
      for (int ct = 0; ct < 2; ++ct)
#pragma unroll
        for (int r = 0; r < 4; ++r) {
          const int srow = rt * 16 + l4 * 4 + r;
          const int scol = wid * 32 + ct * 16 + ln15;
          stash[srow * STASH_LD + scol] = f2bf(acc[rt][ct][r]);
        }
    __syncthreads();

    // ---- fused GRU epilogue for this 32-col chunk ----
    for (int idx = tid; idx < BM * 32; idx += TPB) {
      const int r = idx >> 5;
      const int oc = idx & 31;
      const int grow = row0 + r;
      if (grow < nn) {
        const int col = cc * 32 + oc;
        const ushort* srow = &stash[r * STASH_LD];
        float gir = bf2f(srow[oc])        + b_ih[col];
        float giz = bf2f(srow[32 + oc])   + b_ih[256 + col];
        float gin = bf2f(srow[64 + oc])   + b_ih[512 + col];
        float ghr = bf2f(srow[96 + oc])   + b_hh[col];
        float ghz = bf2f(srow[128 + oc])  + b_hh[256 + col];
        float ghn = bf2f(srow[160 + oc])  + b_hh[512 + col];
        float rr = 1.f / (1.f + __expf(-(gir + ghr)));
        float zz = 1.f / (1.f + __expf(-(giz + ghz)));
        float n_ = tanhf(gin + rr * ghn);
        float hv = hmat[(size_t)grow * H + col];
        out[(size_t)grow * H + col] = (1.f - zz) * n_ + zz * hv;
      }
    }
    __syncthreads();
  }
}

extern "C" void kernel_launch(void* const* d_in, const int* in_sizes, int n_in,
                              void* d_out, int out_size, void* d_ws, size_t ws_size,
                              hipStream_t stream) {
  const float* h    = (const float*)d_in[0];
  const float* relv = (const float*)d_in[1];
  const float* w_ih = (const float*)d_in[2];
  const float* w_hh = (const float*)d_in[3];
  const float* b_ih = (const float*)d_in[4];
  const float* b_hh = (const float*)d_in[5];
  const int* esrc   = (const int*)d_in[6];
  const int* edst   = (const int*)d_in[7];
  const int* erel   = (const int*)d_in[8];
  float* out = (float*)d_out;
  const int nn = in_sizes[0] / H;   // 50000
  const int ne = in_sizes[6];       // 800000
  const int nw = in_sizes[2];       // 768*256

  // ---- workspace layout (bytes) ----
  char* w = (char*)d_ws;
  ushort* red16 = (ushort*)w;                        w += (size_t)nn * H * 2;   // 25.6 MB
  ushort* h16   = (ushort*)w;                        w += (size_t)nn * H * 2;   // 25.6 MB
  ushort* wih16 = (ushort*)w;                        w += (size_t)nw * 2;
  ushort* whh16 = (ushort*)w;                        w += (size_t)nw * 2;
  int* cnt    = (int*)w;                             w += (size_t)nn * 4;
  int* offs   = (int*)w;                             w += (size_t)(nn + 4) * 4;
  int* cursor = (int*)w;                             w += (size_t)nn * 4;
  int* bucket = (int*)w;                             // ne ints

  // bf16 conversions
  k_cvt<<<(nn * H / 4 + 255) / 256, 256, 0, stream>>>(h, h16, nn * H / 4);
  k_cvt<<<(nw / 4 + 255) / 256, 256, 0, stream>>>(w_ih, wih16, nw / 4);
  k_cvt<<<(nw / 4 + 255) / 256, 256, 0, stream>>>(w_hh, whh16, nw / 4);

  // CSR build
  k_zero<<<(nn + 255) / 256, 256, 0, stream>>>(cnt, nn);
  k_hist<<<(ne + 255) / 256, 256, 0, stream>>>(edst, cnt, ne);
  k_scan<<<1, 1024, 0, stream>>>(cnt, offs, cursor, nn);
  k_fill<<<(ne + 255) / 256, 256, 0, stream>>>(esrc, edst, erel, cursor, bucket, ne);

  // gather-reduce
  k_gather<<<(nn + 3) / 4, 256, 0, stream>>>(h16, relv, offs, bucket, red16, nn);

  // fused MFMA GEMM + GRU
  k_gru_mfma<<<(nn + BM - 1) / BM, TPB, 0, stream>>>(red16, h16, h, wih16, whh16,
                                                     b_ih, b_hh, out, nn);
}

// Round 4
// 443.321 us; speedup vs baseline: 4.3535x; 1.5928x over previous
//
#include <hip/hip_runtime.h>

#define H 256

typedef __attribute__((ext_vector_type(8))) short short8;
typedef __attribute__((ext_vector_type(8))) unsigned short ushort8v;
typedef __attribute__((ext_vector_type(16))) float f32x16;

__device__ __forceinline__ ushort f2bf(float f) {
  unsigned u = __float_as_uint(f);
  unsigned r = (u + 0x7fffu + ((u >> 16) & 1u)) >> 16;
  return (ushort)r;
}
__device__ __forceinline__ float bf2f(ushort s) {
  return __uint_as_float(((unsigned)s) << 16);
}
__device__ __forceinline__ void gld_lds16(const void* g, void* lds) {
  __builtin_amdgcn_global_load_lds(
      (const __attribute__((address_space(1))) unsigned int*)g,
      (__attribute__((address_space(3))) unsigned int*)lds, 16, 0, 0);
}

// ---------- f32 -> bf16 convert ----------
__global__ void k_cvt(const float* __restrict__ src, ushort* __restrict__ dst, int n4) {
  int i = blockIdx.x * blockDim.x + threadIdx.x;
  if (i < n4) {
    float4 f = *(const float4*)&src[(size_t)i * 4];
    ushort4 o;
    o.x = f2bf(f.x); o.y = f2bf(f.y); o.z = f2bf(f.z); o.w = f2bf(f.w);
    *(ushort4*)&dst[(size_t)i * 4] = o;
  }
}

// ---------- CSR build ----------
__global__ void k_zero(int* cnt, int n) {
  int i = blockIdx.x * blockDim.x + threadIdx.x;
  if (i < n) cnt[i] = 0;
}

__global__ void k_hist(const int* __restrict__ dst, int* __restrict__ cnt, int ne) {
  int e = blockIdx.x * blockDim.x + threadIdx.x;
  if (e < ne) atomicAdd(&cnt[dst[e]], 1);
}

// hierarchical scan: block sums -> scan sums -> per-block scan + add
__global__ __launch_bounds__(256) void k_scan1(const int* __restrict__ cnt,
                                               int* __restrict__ bsum, int n) {
  __shared__ int s[256];
  int t = threadIdx.x, i = blockIdx.x * 256 + t;
  int v = (i < n) ? cnt[i] : 0;
  s[t] = v;
  __syncthreads();
  for (int o = 128; o > 0; o >>= 1) {
    if (t < o) s[t] += s[t + o];
    __syncthreads();
  }
  if (t == 0) bsum[blockIdx.x] = s[0];
}

__global__ __launch_bounds__(256) void k_scan2(const int* __restrict__ bsum,
                                               int* __restrict__ bpre, int nb,
                                               int* __restrict__ offs, int n) {
  __shared__ int s[256];
  int t = threadIdx.x;
  int v = (t < nb) ? bsum[t] : 0;
  s[t] = v;
  __syncthreads();
  for (int o = 1; o < 256; o <<= 1) {
    int x = (t >= o) ? s[t - o] : 0;
    __syncthreads();
    s[t] += x;
    __syncthreads();
  }
  if (t < nb) bpre[t] = s[t] - v;
  if (t == 255) offs[n] = s[255];
}

__global__ __launch_bounds__(256) void k_scan3(const int* __restrict__ cnt,
                                               const int* __restrict__ bpre,
                                               int* __restrict__ offs,
                                               int* __restrict__ cursor, int n) {
  __shared__ int s[256];
  int t = threadIdx.x, i = blockIdx.x * 256 + t;
  int v = (i < n) ? cnt[i] : 0;
  s[t] = v;
  __syncthreads();
  for (int o = 1; o < 256; o <<= 1) {
    int x = (t >= o) ? s[t - o] : 0;
    __syncthreads();
    s[t] += x;
    __syncthreads();
  }
  if (i < n) {
    int e = bpre[blockIdx.x] + s[t] - v;
    offs[i] = e;
    cursor[i] = e;
  }
}

__global__ void k_fill(const int* __restrict__ src, const int* __restrict__ dst,
                       const int* __restrict__ rel, int* __restrict__ cursor,
                       int* __restrict__ bucket, int ne) {
  int e = blockIdx.x * blockDim.x + threadIdx.x;
  if (e < ne) {
    int p = atomicAdd(&cursor[dst[e]], 1);
    bucket[p] = src[e] | (rel[e] << 16);
  }
}

// ---------- gather-reduce: half-wave (32 lanes x 16B) per node, 2-edge unroll ----------
__global__ __launch_bounds__(256) void k_gather(const ushort* __restrict__ h16,
                                                const float* __restrict__ relv,
                                                const int* __restrict__ offs,
                                                const int* __restrict__ bucket,
                                                ushort* __restrict__ red16, int nn) {
  const int hw = threadIdx.x >> 5;
  const int l = threadIdx.x & 31;
  const int node = blockIdx.x * 8 + hw;
  if (node >= nn) return;
  const int beg = offs[node], end = offs[node + 1];
  float acc[8] = {0.f, 0.f, 0.f, 0.f, 0.f, 0.f, 0.f, 0.f};
  int i = beg;
  for (; i + 2 <= end; i += 2) {
    const int p0 = bucket[i], p1 = bucket[i + 1];
    const ushort8v a0 = *(const ushort8v*)&h16[(size_t)(p0 & 0xFFFF) * H + l * 8];
    const ushort8v a1 = *(const ushort8v*)&h16[(size_t)(p1 & 0xFFFF) * H + l * 8];
    const float4 r0a = *(const float4*)&relv[(p0 >> 16) * H + l * 8];
    const float4 r0b = *(const float4*)&relv[(p0 >> 16) * H + l * 8 + 4];
    const float4 r1a = *(const float4*)&relv[(p1 >> 16) * H + l * 8];
    const float4 r1b = *(const float4*)&relv[(p1 >> 16) * H + l * 8 + 4];
    acc[0] += bf2f(a0[0]) + r0a.x + bf2f(a1[0]) + r1a.x;
    acc[1] += bf2f(a0[1]) + r0a.y + bf2f(a1[1]) + r1a.y;
    acc[2] += bf2f(a0[2]) + r0a.z + bf2f(a1[2]) + r1a.z;
    acc[3] += bf2f(a0[3]) + r0a.w + bf2f(a1[3]) + r1a.w;
    acc[4] += bf2f(a0[4]) + r0b.x + bf2f(a1[4]) + r1b.x;
    acc[5] += bf2f(a0[5]) + r0b.y + bf2f(a1[5]) + r1b.y;
    acc[6] += bf2f(a0[6]) + r0b.z + bf2f(a1[6]) + r1b.z;
    acc[7] += bf2f(a0[7]) + r0b.w + bf2f(a1[7]) + r1b.w;
  }
  if (i < end) {
    const int p0 = bucket[i];
    const ushort8v a0 = *(const ushort8v*)&h16[(size_t)(p0 & 0xFFFF) * H + l * 8];
    const float4 r0a = *(const float4*)&relv[(p0 >> 16) * H + l * 8];
    const float4 r0b = *(const float4*)&relv[(p0 >> 16) * H + l * 8 + 4];
    acc[0] += bf2f(a0[0]) + r0a.x;
    acc[1] += bf2f(a0[1]) + r0a.y;
    acc[2] += bf2f(a0[2]) + r0a.z;
    acc[3] += bf2f(a0[3]) + r0a.w;
    acc[4] += bf2f(a0[4]) + r0b.x;
    acc[5] += bf2f(a0[5]) + r0b.y;
    acc[6] += bf2f(a0[6]) + r0b.z;
    acc[7] += bf2f(a0[7]) + r0b.w;
  }
  ushort8v o;
#pragma unroll
  for (int e = 0; e < 8; ++e) o[e] = f2bf(acc[e]);
  *(ushort8v*)&red16[(size_t)node * H + l * 8] = o;
}

// ---------- fused dual-GEMM (32x32x16 bf16 MFMA) + GRU ----------
// Block: 512 thr (8 waves), 128 rows x 64 h-cols, 6 gate strips.
// Wave w: mat = w>>2 (0:ih/red, 1:hh/h), rows (w>>1&1)*64 (+0/+32), cols (w&1)*32.
// K=256 in 8 steps of BK=32, double-buffered frag-major LDS:
//   buffer (40960 B): A_red frags [kg2hi(4)][row(128)] @0 (8KB)
//                     A_h same @8192, W frags [kg2hi(4)][gcol(384)] @16384 (24KB)
// Epilogue: hh waves stash acc as bf16 (48KB, reuses buffers), ih waves fuse GRU.
__global__ __launch_bounds__(512, 2) void k_gru_mfma(
    const ushort* __restrict__ red16, const ushort* __restrict__ h16,
    const float* __restrict__ hmat,
    const ushort* __restrict__ wih16, const ushort* __restrict__ whh16,
    const float* __restrict__ b_ih, const float* __restrict__ b_hh,
    float* __restrict__ out, int nn) {
  __shared__ unsigned char smem[81920];
  const int tid = threadIdx.x;
  const int wid = tid >> 6;
  const int lane = tid & 63;
  const int l31 = lane & 31;
  const int lhi = lane >> 5;
  const int row0 = blockIdx.x * 128;
  const int hcol0 = blockIdx.y * 64;

  // --- staging address decode (per-thread constants) ---
  // A regions: frag f = wid*64 + lane -> kg2hi = f>>7, row = f&127
  const int fA = wid * 64 + lane;
  const int A_kg2hi = fA >> 7;
  const int A_row = fA & 127;
  int A_grow = row0 + A_row;
  if (A_grow >= nn) A_grow = nn - 1;
  const size_t A_srcoff = (size_t)A_grow * H + (A_kg2hi >> 1) * 16 + (A_kg2hi & 1) * 8;
  // W region: 3 instrs per wave, frag f = (wid*3+jj)*64 + lane -> kg2hi = f/384, gcol = f%384
  const ushort* W_mat[3];
  size_t W_srcoff[3];
  for (int jj = 0; jj < 3; ++jj) {
    const int f = (wid * 3 + jj) * 64 + lane;
    const int kg2hi = f / 384;
    const int gcol = f % 384;
    const int sg = gcol >> 6, cis = gcol & 63;
    W_mat[jj] = (sg < 3) ? wih16 : whh16;
    const int gate = (sg < 3) ? sg : sg - 3;
    W_srcoff[jj] = (size_t)(gate * 256 + hcol0 + cis) * H + (kg2hi >> 1) * 16 + (kg2hi & 1) * 8;
  }

#define STAGE(bufo, kb) do { \
    const int kboff = (kb) * 32; \
    gld_lds16(red16 + A_srcoff + kboff, &smem[(bufo) + wid * 1024]); \
    gld_lds16(h16 + A_srcoff + kboff, &smem[(bufo) + 8192 + wid * 1024]); \
    gld_lds16(W_mat[0] + W_srcoff[0] + kboff, &smem[(bufo) + 16384 + (wid * 3 + 0) * 1024]); \
    gld_lds16(W_mat[1] + W_srcoff[1] + kboff, &smem[(bufo) + 16384 + (wid * 3 + 1) * 1024]); \
    gld_lds16(W_mat[2] + W_srcoff[2] + kboff, &smem[(bufo) + 16384 + (wid * 3 + 2) * 1024]); \
  } while (0)

  f32x16 acc[2][3] = {};
  const int mato = (wid >= 4) ? 8192 : 0;
  const int sgb = (wid >= 4) ? 3 : 0;
  const int R0 = ((wid >> 1) & 1) * 64;
  const int C = (wid & 1) * 32;

  STAGE(0, 0);
  __syncthreads();
  for (int kb = 0; kb < 8; ++kb) {
    const int bo = (kb & 1) * 40960;
    if (kb < 7) STAGE(40960 - bo, kb + 1);
#pragma unroll
    for (int kg = 0; kg < 2; ++kg) {
      const int ko = kg * 2 + lhi;
      const short8 a0 = *(const short8*)&smem[bo + mato + ko * 2048 + (R0 + l31) * 16];
      const short8 a1 = *(const short8*)&smem[bo + mato + ko * 2048 + (R0 + 32 + l31) * 16];
      const short8 b0 = *(const short8*)&smem[bo + 16384 + ko * 6144 + ((sgb + 0) * 64 + C + l31) * 16];
      const short8 b1 = *(const short8*)&smem[bo + 16384 + ko * 6144 + ((sgb + 1) * 64 + C + l31) * 16];
      const short8 b2 = *(const short8*)&smem[bo + 16384 + ko * 6144 + ((sgb + 2) * 64 + C + l31) * 16];
      acc[0][0] = __builtin_amdgcn_mfma_f32_32x32x16_bf16(a0, b0, acc[0][0], 0, 0, 0);
      acc[0][1] = __builtin_amdgcn_mfma_f32_32x32x16_bf16(a0, b1, acc[0][1], 0, 0, 0);
      acc[0][2] = __builtin_amdgcn_mfma_f32_32x32x16_bf16(a0, b2, acc[0][2], 0, 0, 0);
      acc[1][0] = __builtin_amdgcn_mfma_f32_32x32x16_bf16(a1, b0, acc[1][0], 0, 0, 0);
      acc[1][1] = __builtin_amdgcn_mfma_f32_32x32x16_bf16(a1, b1, acc[1][1], 0, 0, 0);
      acc[1][2] = __builtin_amdgcn_mfma_f32_32x32x16_bf16(a1, b2, acc[1][2], 0, 0, 0);
    }
    __syncthreads();
  }
#undef STAGE

  // --- exchange: hh waves stash gh (bf16) into LDS ---
  if (wid >= 4) {
    const int ww = wid - 4;
#pragma unroll
    for (int rt = 0; rt < 2; ++rt)
#pragma unroll
      for (int s = 0; s < 3; ++s) {
        ushort tmp[16];
#pragma unroll
        for (int r = 0; r < 16; ++r) tmp[r] = f2bf(acc[rt][s][r]);
        const int so = ww * 12288 + (rt * 3 + s) * 2048 + lane * 32;
        *(ushort8v*)&smem[so] = *(const ushort8v*)&tmp[0];
        *(ushort8v*)&smem[so + 16] = *(const ushort8v*)&tmp[8];
      }
  }
  __syncthreads();

  // --- ih waves: fused GRU epilogue ---
  if (wid < 4) {
    const int hcol = hcol0 + C + l31;
    const float bir = b_ih[hcol], biz = b_ih[256 + hcol], bin = b_ih[512 + hcol];
    const float bhr = b_hh[hcol], bhz = b_hh[256 + hcol], bhn = b_hh[512 + hcol];
#pragma unroll
    for (int rt = 0; rt < 2; ++rt) {
      ushort hr_[16], hz_[16], hn_[16];
      const int so = wid * 12288 + rt * 3 * 2048 + lane * 32;
      *(ushort8v*)&hr_[0] = *(const ushort8v*)&smem[so];
      *(ushort8v*)&hr_[8] = *(const ushort8v*)&smem[so + 16];
      *(ushort8v*)&hz_[0] = *(const ushort8v*)&smem[so + 2048];
      *(ushort8v*)&hz_[8] = *(const ushort8v*)&smem[so + 2048 + 16];
      *(ushort8v*)&hn_[0] = *(const ushort8v*)&smem[so + 4096];
      *(ushort8v*)&hn_[8] = *(const ushort8v*)&smem[so + 4096 + 16];
#pragma unroll
      for (int r = 0; r < 16; ++r) {
        const int rowc = (r & 3) + 8 * (r >> 2) + 4 * lhi;
        const int grow = row0 + R0 + rt * 32 + rowc;
        if (grow < nn) {
          const float ir_ = acc[rt][0][r] + bir;
          const float iz_ = acc[rt][1][r] + biz;
          const float in_ = acc[rt][2][r] + bin;
          const float hr = bf2f(hr_[r]) + bhr;
          const float hz = bf2f(hz_[r]) + bhz;
          const float hn = bf2f(hn_[r]) + bhn;
          const float rg = 1.f / (1.f + __expf(-(ir_ + hr)));
          const float zg = 1.f / (1.f + __expf(-(iz_ + hz)));
          const float ng = tanhf(in_ + rg * hn);
          const float hv = hmat[(size_t)grow * H + hcol];
          out[(size_t)grow * H + hcol] = (1.f - zg) * ng + zg * hv;
        }
      }
    }
  }
}

extern "C" void kernel_launch(void* const* d_in, const int* in_sizes, int n_in,
                              void* d_out, int out_size, void* d_ws, size_t ws_size,
                              hipStream_t stream) {
  const float* h    = (const float*)d_in[0];
  const float* relv = (const float*)d_in[1];
  const float* w_ih = (const float*)d_in[2];
  const float* w_hh = (const float*)d_in[3];
  const float* b_ih = (const float*)d_in[4];
  const float* b_hh = (const float*)d_in[5];
  const int* esrc   = (const int*)d_in[6];
  const int* edst   = (const int*)d_in[7];
  const int* erel   = (const int*)d_in[8];
  float* out = (float*)d_out;
  const int nn = in_sizes[0] / H;   // 50000
  const int ne = in_sizes[6];       // 800000
  const int nw = in_sizes[2];       // 768*256
  const int nb = (nn + 255) / 256;  // 196

  // ---- workspace layout ----
  char* w = (char*)d_ws;
  ushort* red16 = (ushort*)w;  w += (size_t)nn * H * 2;
  ushort* h16   = (ushort*)w;  w += (size_t)nn * H * 2;
  ushort* wih16 = (ushort*)w;  w += (size_t)nw * 2;
  ushort* whh16 = (ushort*)w;  w += (size_t)nw * 2;
  int* cnt    = (int*)w;       w += (size_t)nn * 4;
  int* offs   = (int*)w;       w += (size_t)(nn + 4) * 4;
  int* cursor = (int*)w;       w += (size_t)nn * 4;
  int* bsum   = (int*)w;       w += 256 * 4;
  int* bpre   = (int*)w;       w += 256 * 4;
  int* bucket = (int*)w;

  k_cvt<<<(nn * H / 4 + 255) / 256, 256, 0, stream>>>(h, h16, nn * H / 4);
  k_cvt<<<(nw / 4 + 255) / 256, 256, 0, stream>>>(w_ih, wih16, nw / 4);
  k_cvt<<<(nw / 4 + 255) / 256, 256, 0, stream>>>(w_hh, whh16, nw / 4);

  k_zero<<<(nn + 255) / 256, 256, 0, stream>>>(cnt, nn);
  k_hist<<<(ne + 255) / 256, 256, 0, stream>>>(edst, cnt, ne);
  k_scan1<<<nb, 256, 0, stream>>>(cnt, bsum, nn);
  k_scan2<<<1, 256, 0, stream>>>(bsum, bpre, nb, offs, nn);
  k_scan3<<<nb, 256, 0, stream>>>(cnt, bpre, offs, cursor, nn);
  k_fill<<<(ne + 255) / 256, 256, 0, stream>>>(esrc, edst, erel, cursor, bucket, ne);

  k_gather<<<(nn + 7) / 8, 256, 0, stream>>>(h16, relv, offs, bucket, red16, nn);

  dim3 grid((nn + 127) / 128, 4);
  k_gru_mfma<<<grid, 512, 0, stream>>>(red16, h16, h, wih16, whh16, b_ih, b_hh, out, nn);
}

// Round 5
// 407.441 us; speedup vs baseline: 4.7369x; 1.0881x over previous
//
#include <hip/hip_runtime.h>

#define H 256

typedef __attribute__((ext_vector_type(8))) short short8;
typedef __attribute__((ext_vector_type(8))) unsigned short ushort8v;
typedef __attribute__((ext_vector_type(16))) float f32x16;

__device__ __forceinline__ ushort f2bf(float f) {
  unsigned u = __float_as_uint(f);
  unsigned r = (u + 0x7fffu + ((u >> 16) & 1u)) >> 16;
  return (ushort)r;
}
__device__ __forceinline__ float bf2f(ushort s) {
  return __uint_as_float(((unsigned)s) << 16);
}

// ============ frag-major layouts ============
// A-type (red, h): panel p = row>>7, r = row&127; chunk l = k>>3 (0..31).
//   byte addr = p*65536 + l*2048 + r*16   (panel = 64 KB)
// W (both mats, gidx = [ih: gate*256+col | hh: 768+gate*256+col]):
//   byte addr = l*24576 + gidx*16         (l = k>>3, 0..31; total 768 KB)

// ---------- h: f32 -> bf16 row-major (for gather) + frag-major (for GEMM) ----------
__global__ void k_cvt_h(const float* __restrict__ src, ushort* __restrict__ h16row,
                        ushort* __restrict__ hfm, int nrows) {
  int t = blockIdx.x * blockDim.x + threadIdx.x;
  if (t >= nrows * 32) return;
  const int row = t >> 5, l = t & 31;
  const float4 fa = *(const float4*)&src[(size_t)row * H + l * 8];
  const float4 fb = *(const float4*)&src[(size_t)row * H + l * 8 + 4];
  ushort8v o;
  o[0] = f2bf(fa.x); o[1] = f2bf(fa.y); o[2] = f2bf(fa.z); o[3] = f2bf(fa.w);
  o[4] = f2bf(fb.x); o[5] = f2bf(fb.y); o[6] = f2bf(fb.z); o[7] = f2bf(fb.w);
  *(ushort8v*)&h16row[(size_t)row * H + l * 8] = o;
  const int p = row >> 7, r = row & 127;
  *(ushort8v*)((char*)hfm + (size_t)p * 65536 + (size_t)l * 2048 + r * 16) = o;
}

// ---------- W: f32 -> bf16 frag-major ----------
__global__ void k_cvt_w(const float* __restrict__ w, ushort* __restrict__ wfm, int gbase) {
  int t = blockIdx.x * blockDim.x + threadIdx.x;
  if (t >= 768 * 32) return;
  const int j = t >> 5, l = t & 31;
  const float4 fa = *(const float4*)&w[(size_t)j * H + l * 8];
  const float4 fb = *(const float4*)&w[(size_t)j * H + l * 8 + 4];
  ushort8v o;
  o[0] = f2bf(fa.x); o[1] = f2bf(fa.y); o[2] = f2bf(fa.z); o[3] = f2bf(fa.w);
  o[4] = f2bf(fb.x); o[5] = f2bf(fb.y); o[6] = f2bf(fb.z); o[7] = f2bf(fb.w);
  *(ushort8v*)((char*)wfm + ((size_t)l * 1536 + gbase + j) * 16) = o;
}

// ---------- CSR build ----------
__global__ void k_zero(int* cnt, int n) {
  int i = blockIdx.x * blockDim.x + threadIdx.x;
  if (i < n) cnt[i] = 0;
}

__global__ void k_hist(const int* __restrict__ dst, int* __restrict__ cnt, int ne) {
  int e = blockIdx.x * blockDim.x + threadIdx.x;
  if (e < ne) atomicAdd(&cnt[dst[e]], 1);
}

__global__ __launch_bounds__(256) void k_scan1(const int* __restrict__ cnt,
                                               int* __restrict__ bsum, int n) {
  __shared__ int s[256];
  int t = threadIdx.x, i = blockIdx.x * 256 + t;
  int v = (i < n) ? cnt[i] : 0;
  s[t] = v;
  __syncthreads();
  for (int o = 128; o > 0; o >>= 1) {
    if (t < o) s[t] += s[t + o];
    __syncthreads();
  }
  if (t == 0) bsum[blockIdx.x] = s[0];
}

__global__ __launch_bounds__(256) void k_scan2(const int* __restrict__ bsum,
                                               int* __restrict__ bpre, int nb,
                                               int* __restrict__ offs, int n) {
  __shared__ int s[256];
  int t = threadIdx.x;
  int v = (t < nb) ? bsum[t] : 0;
  s[t] = v;
  __syncthreads();
  for (int o = 1; o < 256; o <<= 1) {
    int x = (t >= o) ? s[t - o] : 0;
    __syncthreads();
    s[t] += x;
    __syncthreads();
  }
  if (t < nb) bpre[t] = s[t] - v;
  if (t == 255) offs[n] = s[255];
}

__global__ __launch_bounds__(256) void k_scan3(const int* __restrict__ cnt,
                                               const int* __restrict__ bpre,
                                               int* __restrict__ offs,
                                               int* __restrict__ cursor, int n) {
  __shared__ int s[256];
  int t = threadIdx.x, i = blockIdx.x * 256 + t;
  int v = (i < n) ? cnt[i] : 0;
  s[t] = v;
  __syncthreads();
  for (int o = 1; o < 256; o <<= 1) {
    int x = (t >= o) ? s[t - o] : 0;
    __syncthreads();
    s[t] += x;
    __syncthreads();
  }
  if (i < n) {
    int e = bpre[blockIdx.x] + s[t] - v;
    offs[i] = e;
    cursor[i] = e;
  }
}

__global__ void k_fill(const int* __restrict__ src, const int* __restrict__ dst,
                       const int* __restrict__ rel, int* __restrict__ cursor,
                       int* __restrict__ bucket, int ne) {
  int e = blockIdx.x * blockDim.x + threadIdx.x;
  if (e < ne) {
    int p = atomicAdd(&cursor[dst[e]], 1);
    bucket[p] = src[e] | (rel[e] << 16);
  }
}

// ---------- gather-reduce: half-wave per node; writes red in FRAG-MAJOR ----------
__global__ __launch_bounds__(256) void k_gather(const ushort* __restrict__ h16,
                                                const float* __restrict__ relv,
                                                const int* __restrict__ offs,
                                                const int* __restrict__ bucket,
                                                ushort* __restrict__ redfm, int nn) {
  const int hw = threadIdx.x >> 5;
  const int l = threadIdx.x & 31;
  const int node = blockIdx.x * 8 + hw;
  if (node >= nn) return;
  const int beg = offs[node], end = offs[node + 1];
  float acc[8] = {0.f, 0.f, 0.f, 0.f, 0.f, 0.f, 0.f, 0.f};
  int i = beg;
  for (; i + 2 <= end; i += 2) {
    const int p0 = bucket[i], p1 = bucket[i + 1];
    const ushort8v a0 = *(const ushort8v*)&h16[(size_t)(p0 & 0xFFFF) * H + l * 8];
    const ushort8v a1 = *(const ushort8v*)&h16[(size_t)(p1 & 0xFFFF) * H + l * 8];
    const float4 r0a = *(const float4*)&relv[(p0 >> 16) * H + l * 8];
    const float4 r0b = *(const float4*)&relv[(p0 >> 16) * H + l * 8 + 4];
    const float4 r1a = *(const float4*)&relv[(p1 >> 16) * H + l * 8];
    const float4 r1b = *(const float4*)&relv[(p1 >> 16) * H + l * 8 + 4];
    acc[0] += bf2f(a0[0]) + r0a.x + bf2f(a1[0]) + r1a.x;
    acc[1] += bf2f(a0[1]) + r0a.y + bf2f(a1[1]) + r1a.y;
    acc[2] += bf2f(a0[2]) + r0a.z + bf2f(a1[2]) + r1a.z;
    acc[3] += bf2f(a0[3]) + r0a.w + bf2f(a1[3]) + r1a.w;
    acc[4] += bf2f(a0[4]) + r0b.x + bf2f(a1[4]) + r1b.x;
    acc[5] += bf2f(a0[5]) + r0b.y + bf2f(a1[5]) + r1b.y;
    acc[6] += bf2f(a0[6]) + r0b.z + bf2f(a1[6]) + r1b.z;
    acc[7] += bf2f(a0[7]) + r0b.w + bf2f(a1[7]) + r1b.w;
  }
  if (i < end) {
    const int p0 = bucket[i];
    const ushort8v a0 = *(const ushort8v*)&h16[(size_t)(p0 & 0xFFFF) * H + l * 8];
    const float4 r0a = *(const float4*)&relv[(p0 >> 16) * H + l * 8];
    const float4 r0b = *(const float4*)&relv[(p0 >> 16) * H + l * 8 + 4];
    acc[0] += bf2f(a0[0]) + r0a.x;
    acc[1] += bf2f(a0[1]) + r0a.y;
    acc[2] += bf2f(a0[2]) + r0a.z;
    acc[3] += bf2f(a0[3]) + r0a.w;
    acc[4] += bf2f(a0[4]) + r0b.x;
    acc[5] += bf2f(a0[5]) + r0b.y;
    acc[6] += bf2f(a0[6]) + r0b.z;
    acc[7] += bf2f(a0[7]) + r0b.w;
  }
  ushort8v o;
#pragma unroll
  for (int e = 0; e < 8; ++e) o[e] = f2bf(acc[e]);
  const int p = node >> 7, r = node & 127;
  *(ushort8v*)((char*)redfm + (size_t)p * 65536 + (size_t)l * 2048 + r * 16) = o;
}

// ---------- fused dual-GEMM (32x32x16 bf16 MFMA, register-direct) + GRU ----------
// Grid (391, 4): block = 128 rows (panel blockIdx.x) x 64 h-cols (blockIdx.y).
// 8 waves: wid<4 -> ih (A=redfm, W gidx base 0); wid>=4 -> hh (A=hfm, base 768).
// Wave sub-tile: rows R0=((wid>>1)&1)*64 (2x32), cols C=(wid&1)*32, 3 gate strips.
// NO LDS / NO barriers in K-loop: frag-major global layout makes every A/B
// fragment a 2x512B contiguous global_load_dwordx4 (L2/L3-resident).
__global__ __launch_bounds__(512, 2) void k_gru_mfma(
    const ushort* __restrict__ redfm, const ushort* __restrict__ hfm,
    const float* __restrict__ hmat, const ushort* __restrict__ wfm,
    const float* __restrict__ b_ih, const float* __restrict__ b_hh,
    float* __restrict__ out, int nn) {
  __shared__ unsigned char smem[49152];
  const int tid = threadIdx.x;
  const int wid = tid >> 6;
  const int lane = tid & 63;
  const int l31 = lane & 31;
  const int lhi = lane >> 5;
  const int row0 = blockIdx.x * 128;
  const int hcol0 = blockIdx.y * 64;
  const bool is_hh = (wid >= 4);
  const int R0 = ((wid >> 1) & 1) * 64;
  const int C = (wid & 1) * 32;

  const char* amat = (const char*)(is_hh ? hfm : redfm);
  const char* wbase = (const char*)wfm;
  // per-wave constant offsets
  const size_t a_base = (size_t)blockIdx.x * 65536 + (size_t)lhi * 2048 + (size_t)(R0 + l31) * 16;
  const size_t b_base = (size_t)lhi * 24576 + (size_t)((is_hh ? 768 : 0) + hcol0 + C + l31) * 16;

  f32x16 acc[2][3] = {};
#pragma unroll 2
  for (int kb = 0; kb < 8; ++kb) {
#pragma unroll
    for (int kg = 0; kg < 2; ++kg) {
      const size_t ao = a_base + (size_t)(kb * 8192 + kg * 4096);
      const size_t bo = b_base + (size_t)(kb * 4 + kg * 2) * 24576;
      const short8 a0 = *(const short8*)(amat + ao);
      const short8 a1 = *(const short8*)(amat + ao + 512);        // +32 rows
      const short8 b0 = *(const short8*)(wbase + bo);             // gate r
      const short8 b1 = *(const short8*)(wbase + bo + 4096);      // gate z (+256 gidx)
      const short8 b2 = *(const short8*)(wbase + bo + 8192);      // gate n (+512 gidx)
      acc[0][0] = __builtin_amdgcn_mfma_f32_32x32x16_bf16(a0, b0, acc[0][0], 0, 0, 0);
      acc[0][1] = __builtin_amdgcn_mfma_f32_32x32x16_bf16(a0, b1, acc[0][1], 0, 0, 0);
      acc[0][2] = __builtin_amdgcn_mfma_f32_32x32x16_bf16(a0, b2, acc[0][2], 0, 0, 0);
      acc[1][0] = __builtin_amdgcn_mfma_f32_32x32x16_bf16(a1, b0, acc[1][0], 0, 0, 0);
      acc[1][1] = __builtin_amdgcn_mfma_f32_32x32x16_bf16(a1, b1, acc[1][1], 0, 0, 0);
      acc[1][2] = __builtin_amdgcn_mfma_f32_32x32x16_bf16(a1, b2, acc[1][2], 0, 0, 0);
    }
  }

  // --- exchange: hh waves stash gh (bf16) into LDS ---
  if (is_hh) {
    const int ww = wid - 4;
#pragma unroll
    for (int rt = 0; rt < 2; ++rt)
#pragma unroll
      for (int s = 0; s < 3; ++s) {
        ushort tmp[16];
#pragma unroll
        for (int r = 0; r < 16; ++r) tmp[r] = f2bf(acc[rt][s][r]);
        const int so = ww * 12288 + (rt * 3 + s) * 2048 + lane * 32;
        *(ushort8v*)&smem[so] = *(const ushort8v*)&tmp[0];
        *(ushort8v*)&smem[so + 16] = *(const ushort8v*)&tmp[8];
      }
  }
  __syncthreads();

  // --- ih waves: fused GRU epilogue ---
  if (!is_hh) {
    const int hcol = hcol0 + C + l31;
    const float bir = b_ih[hcol], biz = b_ih[256 + hcol], bin = b_ih[512 + hcol];
    const float bhr = b_hh[hcol], bhz = b_hh[256 + hcol], bhn = b_hh[512 + hcol];
#pragma unroll
    for (int rt = 0; rt < 2; ++rt) {
      ushort hr_[16], hz_[16], hn_[16];
      const int so = wid * 12288 + rt * 3 * 2048 + lane * 32;
      *(ushort8v*)&hr_[0] = *(const ushort8v*)&smem[so];
      *(ushort8v*)&hr_[8] = *(const ushort8v*)&smem[so + 16];
      *(ushort8v*)&hz_[0] = *(const ushort8v*)&smem[so + 2048];
      *(ushort8v*)&hz_[8] = *(const ushort8v*)&smem[so + 2048 + 16];
      *(ushort8v*)&hn_[0] = *(const ushort8v*)&smem[so + 4096];
      *(ushort8v*)&hn_[8] = *(const ushort8v*)&smem[so + 4096 + 16];
#pragma unroll
      for (int r = 0; r < 16; ++r) {
        const int rowc = (r & 3) + 8 * (r >> 2) + 4 * lhi;
        const int grow = row0 + R0 + rt * 32 + rowc;
        if (grow < nn) {
          const float ir_ = acc[rt][0][r] + bir;
          const float iz_ = acc[rt][1][r] + biz;
          const float in_ = acc[rt][2][r] + bin;
          const float hr = bf2f(hr_[r]) + bhr;
          const float hz = bf2f(hz_[r]) + bhz;
          const float hn = bf2f(hn_[r]) + bhn;
          const float rg = 1.f / (1.f + __expf(-(ir_ + hr)));
          const float zg = 1.f / (1.f + __expf(-(iz_ + hz)));
          const float ng = tanhf(in_ + rg * hn);
          const float hv = hmat[(size_t)grow * H + hcol];
          out[(size_t)grow * H + hcol] = (1.f - zg) * ng + zg * hv;
        }
      }
    }
  }
}

extern "C" void kernel_launch(void* const* d_in, const int* in_sizes, int n_in,
                              void* d_out, int out_size, void* d_ws, size_t ws_size,
                              hipStream_t stream) {
  const float* h    = (const float*)d_in[0];
  const float* relv = (const float*)d_in[1];
  const float* w_ih = (const float*)d_in[2];
  const float* w_hh = (const float*)d_in[3];
  const float* b_ih = (const float*)d_in[4];
  const float* b_hh = (const float*)d_in[5];
  const int* esrc   = (const int*)d_in[6];
  const int* edst   = (const int*)d_in[7];
  const int* erel   = (const int*)d_in[8];
  float* out = (float*)d_out;
  const int nn = in_sizes[0] / H;        // 50000
  const int ne = in_sizes[6];            // 800000
  const int npan = (nn + 127) / 128;     // 391
  const int nb = (nn + 255) / 256;       // 196

  // ---- workspace layout ----
  char* w = (char*)d_ws;
  ushort* redfm  = (ushort*)w;  w += (size_t)npan * 65536;       // 25.6 MB frag-major
  ushort* hfm    = (ushort*)w;  w += (size_t)npan * 65536;       // 25.6 MB frag-major
  ushort* h16row = (ushort*)w;  w += (size_t)nn * H * 2;         // 25.6 MB row-major
  ushort* wfm    = (ushort*)w;  w += (size_t)32 * 1536 * 16;     // 768 KB frag-major
  int* cnt    = (int*)w;        w += (size_t)nn * 4;
  int* offs   = (int*)w;        w += (size_t)(nn + 4) * 4;
  int* cursor = (int*)w;        w += (size_t)nn * 4;
  int* bsum   = (int*)w;        w += 256 * 4;
  int* bpre   = (int*)w;        w += 256 * 4;
  int* bucket = (int*)w;

  k_cvt_h<<<(nn * 32 + 255) / 256, 256, 0, stream>>>(h, h16row, hfm, nn);
  k_cvt_w<<<96, 256, 0, stream>>>(w_ih, wfm, 0);
  k_cvt_w<<<96, 256, 0, stream>>>(w_hh, wfm, 768);

  k_zero<<<(nn + 255) / 256, 256, 0, stream>>>(cnt, nn);
  k_hist<<<(ne + 255) / 256, 256, 0, stream>>>(edst, cnt, ne);
  k_scan1<<<nb, 256, 0, stream>>>(cnt, bsum, nn);
  k_scan2<<<1, 256, 0, stream>>>(bsum, bpre, nb, offs, nn);
  k_scan3<<<nb, 256, 0, stream>>>(cnt, bpre, offs, cursor, nn);
  k_fill<<<(ne + 255) / 256, 256, 0, stream>>>(esrc, edst, erel, cursor, bucket, ne);

  k_gather<<<(nn + 7) / 8, 256, 0, stream>>>(h16row, relv, offs, bucket, redfm, nn);

  dim3 grid(npan, 4);
  k_gru_mfma<<<grid, 512, 0, stream>>>(redfm, hfm, h, wfm, b_ih, b_hh, out, nn);
}